// Round 1
// baseline (43.904 us; speedup 1.0000x reference)
//
#include <hip/hip_runtime.h>
#include <math.h>

#define WID 64
#define HEI 64
#define WH 4096  // WID*HEI

// One block processes 1/4 of one batch's 4096 pixels.
// 256 threads x float4 = 1024 pixels/block, 4 blocks/batch.
__global__ __launch_bounds__(256) void render_kernel(
    const float* __restrict__ depth,    // (B,1,64,64)
    const float* __restrict__ rotates,  // (B,3) degrees
    const float* __restrict__ trans,    // (B,3)
    float* __restrict__ out,            // (B,3,64,64)
    float inv_f)
{
    const int blk   = blockIdx.x;
    const int b     = blk >> 2;
    const int chunk = blk & 3;
    const int tid   = threadIdx.x;

    // reference: _rot_mats(alpha=rot[:,2], beta=rot[:,0], gamma=rot[:,1])
    const float d2r = 0.017453292519943295f;
    const float alpha = rotates[b*3 + 2] * d2r;
    const float beta  = rotates[b*3 + 0] * d2r;
    const float gamma = rotates[b*3 + 1] * d2r;
    const float sa = __sinf(alpha), ca = __cosf(alpha);
    const float sb = __sinf(beta),  cb = __cosf(beta);
    const float sg = __sinf(gamma), cg = __cosf(gamma);

    // rot_g has the reference's bug: rot_g[2][0] = -sin(alpha), not -sin(gamma).
    // T = rot_b @ rot_g
    const float T00 = cg;       const float T01 = 0.0f; const float T02 = sg;
    const float T10 = sa * sb;  const float T11 = cb;   const float T12 = -sb * cg;
    const float T20 = -sa * cb; const float T21 = sb;   const float T22 = cb * cg;
    // R = rot_a @ T
    const float R00 = ca * T00 - sa * T10;
    const float R01 = ca * T01 - sa * T11;
    const float R02 = ca * T02 - sa * T12;
    const float R10 = sa * T00 + ca * T10;
    const float R11 = sa * T01 + ca * T11;
    const float R12 = sa * T02 + ca * T12;
    const float R20 = T20, R21 = T21, R22 = T22;

    const float tx = trans[b*3 + 0];
    const float ty = trans[b*3 + 1];
    const float tz = trans[b*3 + 2] + 1.0f;  // + center_z ((0.9+1.1)/2)

    const int   p0 = chunk * 1024 + tid * 4;       // pixel index base
    const int   w  = p0 >> 6;                       // H=64
    const int   h0 = p0 & 63;
    const float rx = ((float)w - 31.5f) * inv_f;    // ray_x, constant over the 4 pixels

    const float4 d4 = *reinterpret_cast<const float4*>(depth + (size_t)b * WH + p0);
    const float dv[4] = { d4.x, d4.y, d4.z, d4.w };

    float ox[4], oy[4], oz[4];
#pragma unroll
    for (int j = 0; j < 4; ++j) {
        const float dd = dv[j];
        const float px = rx * dd;
        const float py = (((float)(h0 + j)) - 31.5f) * inv_f * dd;
        const float pz = dd - 1.0f;                 // center z = 1.0
        ox[j] = R00 * px + R01 * py + R02 * pz + tx;
        oy[j] = R10 * px + R11 * py + R12 * pz + ty;
        oz[j] = R20 * px + R21 * py + R22 * pz + tz;
    }

    const size_t base = (size_t)b * 3 * WH + p0;
    *reinterpret_cast<float4*>(out + base)          = make_float4(ox[0], ox[1], ox[2], ox[3]);
    *reinterpret_cast<float4*>(out + base + WH)     = make_float4(oy[0], oy[1], oy[2], oy[3]);
    *reinterpret_cast<float4*>(out + base + 2*WH)   = make_float4(oz[0], oz[1], oz[2], oz[3]);
}

extern "C" void kernel_launch(void* const* d_in, const int* in_sizes, int n_in,
                              void* d_out, int out_size, void* d_ws, size_t ws_size,
                              hipStream_t stream) {
    const float* depth   = (const float*)d_in[0];
    const float* rotates = (const float*)d_in[1];
    const float* trans   = (const float*)d_in[2];
    float* out = (float*)d_out;

    const int B = in_sizes[0] / WH;

    // f = (W-1) / (2*tan(radians(10)/2)); pass 1/f
    const double f  = 63.0 / (2.0 * tan(10.0 * M_PI / 180.0 / 2.0));
    const float inv_f = (float)(1.0 / f);

    dim3 grid(B * 4);
    dim3 block(256);
    render_kernel<<<grid, block, 0, stream>>>(depth, rotates, trans, out, inv_f);
}